// Round 1
// baseline (63.166 us; speedup 1.0000x reference)
//
#include <hip/hip_runtime.h>
#include <math.h>

#define NMAT (192*192*192)   // 7,077,888 matrices; exactly 27648 blocks of 256

__global__ __launch_bounds__(256) void eig3_kernel(const float* __restrict__ H,
                                                   float* __restrict__ out) {
    __shared__ float lds[256 * 9];
    const int t = threadIdx.x;
    const long long tile = blockIdx.x;
    const long long base = tile * (256LL * 9);

    // Coalesced global -> LDS staging: 2304 contiguous floats per block.
#pragma unroll
    for (int k = 0; k < 9; ++k)
        lds[t + 256 * k] = H[base + t + 256 * k];
    __syncthreads();

    // Each thread grabs its own 9-float matrix from LDS (2-way bank alias: free).
    float h[9];
#pragma unroll
    for (int j = 0; j < 9; ++j)
        h[j] = lds[t * 9 + j];
    __syncthreads();   // lds is reused for the output stage below

    // q = trace/3
    const float q = (h[0] + h[4] + h[8]) * (1.0f / 3.0f);
    // C = H - q*I (deviatoric)
    const float c00 = h[0] - q, c01 = h[1],     c02 = h[2];
    const float c10 = h[3],     c11 = h[4] - q, c12 = h[5];
    const float c20 = h[6],     c21 = h[7],     c22 = h[8] - q;
    // p = sqrt(||C||_F^2 / 6)
    const float ss = c00*c00 + c01*c01 + c02*c02
                   + c10*c10 + c11*c11 + c12*c12
                   + c20*c20 + c21*c21 + c22*c22;
    const float p = sqrtf(ss * (1.0f / 6.0f));
    const float inv = 1.0f / (p + 1e-10f);
    // B = C / (p + eps)
    const float b00 = c00*inv, b01 = c01*inv, b02 = c02*inv;
    const float b10 = c10*inv, b11 = c11*inv, b12 = c12*inv;
    const float b20 = c20*inv, b21 = c21*inv, b22 = c22*inv;
    const float detB = b00*(b11*b22 - b12*b21)
                     - b01*(b10*b22 - b12*b20)
                     + b02*(b10*b21 - b11*b20);
    const float x = fminf(fmaxf(detB * 0.5f, -1.0f), 1.0f);
    const float theta = acosf(x) * (1.0f / 3.0f);
    const float two_pi_3 = 2.09439510239319549f;  // 2*pi/3
    const float e0 = 2.0f * cosf(theta) * p + q;
    const float e1 = 2.0f * cosf(theta + two_pi_3) * p + q;
    const float e2 = 2.0f * cosf(theta + 2.0f * two_pi_3) * p + q;

    // sort ascending (min/max network)
    const float a  = fminf(e0, e1), b = fmaxf(e0, e1);
    const float hi = fmaxf(b, e2),  c = fminf(b, e2);
    const float lo = fminf(a, c),   mid = fmaxf(a, c);

    // Stage output in LDS, then coalesced store of 768 contiguous floats.
    lds[t * 3 + 0] = lo;
    lds[t * 3 + 1] = mid;
    lds[t * 3 + 2] = hi;
    __syncthreads();

    const long long obase = tile * (256LL * 3);
#pragma unroll
    for (int k = 0; k < 3; ++k)
        out[obase + t + 256 * k] = lds[t + 256 * k];
}

extern "C" void kernel_launch(void* const* d_in, const int* in_sizes, int n_in,
                              void* d_out, int out_size, void* d_ws, size_t ws_size,
                              hipStream_t stream) {
    const float* H = (const float*)d_in[0];
    float* out = (float*)d_out;
    const int nblocks = NMAT / 256;  // 27648, no tail
    eig3_kernel<<<nblocks, 256, 0, stream>>>(H, out);
}